// Round 7
// baseline (65.662 us; speedup 1.0000x reference)
//
#include <hip/hip_runtime.h>
#include <hip/hip_bf16.h>

// MoE: out[b] = inp[b] @ weight[gate[b]].T
// inp: [4096,512] f32, gate: [4096] int, weight: [32,512,512] f32, out: [4096,512] f32
// Round 7: NO-LDS direct-fragment GEMM. Each lane loads its own MFMA fragments
// straight from global (A row = srow[lane&15-derived], 8 contiguous floats),
// cvt_pk to bf16 in registers, MFMA. Zero barriers in the K-loop; waves fully
// independent. Ballot-rank self-prep kept from round 6.

#define NE     32
#define NBATCH 4096
#define KF     512
#define NF     512
#define BM     64
#define BN     64
#define TMAX   4             // max token-tiles/expert (256 tokens; mean 128, sd 11)
#define NCHUNK (NBATCH / 64) // 64 ballot chunks
#define NWG    (8 * NE * TMAX)  // 1024 blocks

typedef __attribute__((ext_vector_type(8))) short bf16x8;
typedef __attribute__((ext_vector_type(4))) float f32x4;

__device__ __forceinline__ unsigned cvt2(float lo, float hi) {
    __hip_bfloat162 h = __float22bfloat162_rn(make_float2(lo, hi));
    return *reinterpret_cast<unsigned*>(&h);   // v_cvt_pk_bf16_f32
}

__device__ __forceinline__ bf16x8 pack8(float4 a, float4 b) {
    union { unsigned u[4]; bf16x8 v; } r;
    r.u[0] = cvt2(a.x, a.y); r.u[1] = cvt2(a.z, a.w);
    r.u[2] = cvt2(b.x, b.y); r.u[3] = cvt2(b.z, b.w);
    return r.v;
}

__global__ __launch_bounds__(256)
void moe_fused(const float* __restrict__ inp,
               const int* __restrict__ gate,
               const float* __restrict__ weight,
               float* __restrict__ out) {
    // Bijective XCD-chunk swizzle (1024 blocks, 8 XCDs): chunk = 4 experts ->
    // ~4MB weights per XCD L2; n-tiles of one A-panel adjacent.
    const int bid = blockIdx.x;
    const int swb = (bid & 7) * (NWG / 8) + (bid >> 3);
    const int nb    = swb & 7;
    const int y     = swb >> 3;
    const int e     = y >> 2;
    const int local = y & 3;

    __shared__ int srow[BM];
    __shared__ int chunkinfo[NCHUNK];
    __shared__ int stotal;

    const int tid  = threadIdx.x;
    const int lane = tid & 63;
    const int wid  = tid >> 6;

    // ---- self-prep: rank expert-e tokens with ballots (round-6 proven) ----
    int g[16];
#pragma unroll
    for (int i = 0; i < 16; ++i)
        g[i] = gate[(wid * 16 + i) * 64 + lane];
#pragma unroll
    for (int i = 0; i < 16; ++i) {
        unsigned long long m = __ballot(g[i] == e);
        if (lane == i) chunkinfo[wid * 16 + i] = __popcll(m);
    }
    if (tid < BM) srow[tid] = -1;
    __syncthreads();
    if (tid < NCHUNK) {
        int c = chunkinfo[tid];
        int x = c;
#pragma unroll
        for (int d = 1; d < 64; d <<= 1) {
            int u = __shfl_up(x, d, 64);
            if (lane >= d) x += u;
        }
        chunkinfo[tid] = x - c;
        if (tid == NCHUNK - 1) stotal = x;
    }
    __syncthreads();

    const int total = stotal;
    const int m0    = local * BM;
    if (m0 >= total) return;             // empty tile: frees the CU quickly

#pragma unroll
    for (int i = 0; i < 16; ++i) {
        unsigned long long m = __ballot(g[i] == e);
        int r = chunkinfo[wid * 16 + i] + __popcll(m & ((1ull << lane) - 1ull));
        if (g[i] == e && r >= m0 && r < m0 + BM)
            srow[r - m0] = (wid * 16 + i) * 64 + lane;
    }
    __syncthreads();                     // last barrier in the kernel

    // ---- direct-fragment GEMM: wave quadrant 32x32, no LDS, no barriers ----
    const int wm   = wid & 1;
    const int wn   = wid >> 1;
    const int nblk = nb * BN;
    const int koff = 8 * (lane >> 4);    // fragment k-offset within 32-step

    int rm[2];
    const float* ap[2];
    const float* wp[2];
#pragma unroll
    for (int mi = 0; mi < 2; ++mi) {
        int r = srow[wm * 32 + mi * 16 + (lane & 15)];
        rm[mi] = r;
        // clamp padding rows to row 0: their results are never stored
        ap[mi] = inp + (size_t)(r < 0 ? 0 : r) * KF + koff;
    }
#pragma unroll
    for (int ni = 0; ni < 2; ++ni)
        wp[ni] = weight + (size_t)e * (NF * KF)
               + (size_t)(nblk + wn * 32 + ni * 16 + (lane & 15)) * KF + koff;

    f32x4 acc[2][2];
#pragma unroll
    for (int mi = 0; mi < 2; ++mi)
#pragma unroll
        for (int ni = 0; ni < 2; ++ni) acc[mi][ni] = (f32x4)(0.f);

    // register double-buffer, static indices (full unroll)
    float4 sa[2][2][2], sb[2][2][2];     // [buf][frag][half]

#define LDK(B, KT) do {                                                        \
    _Pragma("unroll") for (int mi = 0; mi < 2; ++mi) {                         \
        sa[B][mi][0] = *(const float4*)(ap[mi] + (KT) * 32);                   \
        sa[B][mi][1] = *(const float4*)(ap[mi] + (KT) * 32 + 4); }             \
    _Pragma("unroll") for (int ni = 0; ni < 2; ++ni) {                         \
        sb[B][ni][0] = *(const float4*)(wp[ni] + (KT) * 32);                   \
        sb[B][ni][1] = *(const float4*)(wp[ni] + (KT) * 32 + 4); } } while (0)

#define FMAK(B) do {                                                           \
    bf16x8 af[2], bfr[2];                                                      \
    _Pragma("unroll") for (int mi = 0; mi < 2; ++mi)                           \
        af[mi] = pack8(sa[B][mi][0], sa[B][mi][1]);                            \
    _Pragma("unroll") for (int ni = 0; ni < 2; ++ni)                           \
        bfr[ni] = pack8(sb[B][ni][0], sb[B][ni][1]);                           \
    _Pragma("unroll") for (int mi = 0; mi < 2; ++mi)                           \
    _Pragma("unroll") for (int ni = 0; ni < 2; ++ni)                           \
        acc[mi][ni] = __builtin_amdgcn_mfma_f32_16x16x32_bf16(                 \
            af[mi], bfr[ni], acc[mi][ni], 0, 0, 0); } while (0)

    LDK(0, 0);
#pragma unroll
    for (int kt = 0; kt < 16; ++kt) {
        if (kt + 1 < 16) LDK((kt + 1) & 1, kt + 1);   // prefetch next k-step
        FMAK(kt & 1);
    }
#undef LDK
#undef FMAK

    // epilogue: D frag col=lane&15 (n), row=(lane>>4)*4+q (m)  [m89-verified]
#pragma unroll
    for (int mi = 0; mi < 2; ++mi)
#pragma unroll
        for (int q = 0; q < 4; ++q) {
            int m = wm * 32 + mi * 16 + (lane >> 4) * 4 + q;
            int row = srow[m];
            if (row >= 0) {
#pragma unroll
                for (int ni = 0; ni < 2; ++ni)
                    out[(size_t)row * NF + nblk + wn * 32 + ni * 16 + (lane & 15)]
                        = acc[mi][ni][q];
            }
        }
}

extern "C" void kernel_launch(void* const* d_in, const int* in_sizes, int n_in,
                              void* d_out, int out_size, void* d_ws, size_t ws_size,
                              hipStream_t stream) {
    const float* inp    = (const float*)d_in[0];
    const int*   gate   = (const int*)d_in[1];
    const float* weight = (const float*)d_in[2];
    float*       out    = (float*)d_out;

    moe_fused<<<NWG, 256, 0, stream>>>(inp, gate, weight, out);
}

// Round 8
// 31.456 us; speedup vs baseline: 2.0874x; 2.0874x over previous
//
#include <hip/hip_runtime.h>
#include <hip/hip_bf16.h>

// MoE: out[b] = inp[b] @ weight[gate[b]].T
// inp: [4096,512] f32, gate: [4096] int, weight: [32,512,512] f32, out: [4096,512] f32
// Round 8: traffic-minimal design. 256 blocks = (expert e, n-tile nb); W-tile
// converted f32->bf16 ONCE into LDS (64KB, swizzled) => weight read exactly once
// (32MB). A read direct-from-global as MFMA fragments (L2-resident per XCD via
// chunked swizzle), depth-2 register prefetch, zero barriers in the K-loop.

#define NE     32
#define NBATCH 4096
#define KF     512
#define NF     512
#define BN     64
#define SROWN  256           // max tokens/expert handled (mean 128, sd 11; r6-validated)
#define NWG    256           // 32 experts x 8 n-tiles
#define NCHUNK 64

typedef __attribute__((ext_vector_type(8))) short bf16x8;
typedef __attribute__((ext_vector_type(4))) float f32x4;

__device__ __forceinline__ unsigned cvt2(float lo, float hi) {
    __hip_bfloat162 h = __float22bfloat162_rn(make_float2(lo, hi));
    return *reinterpret_cast<unsigned*>(&h);   // v_cvt_pk_bf16_f32
}

// W LDS: [col][512 bf16] rows of 1024B; XOR bits 4-6 of k-byte by col&7.
// Same bijection on write (uint2, 8B) and read (b128, 16B) -> safe + conflict-free.
__device__ __forceinline__ int swzW(int col, int kbyte) {
    return col * 1024 + (kbyte ^ ((col & 7) << 4));
}

__global__ __launch_bounds__(512)
void moe_fused(const float* __restrict__ inp,
               const int* __restrict__ gate,
               const float* __restrict__ weight,
               float* __restrict__ out) {
    // XCD-chunked bijective swizzle: XCD k gets swb [k*32,(k+1)*32) = experts
    // [4k,4k+4), all 8 nb of each expert on one XCD -> A rows L2-resident.
    const int bid  = blockIdx.x;
    const int swb  = (bid & 7) * (NWG / 8) + (bid >> 3);
    const int e    = swb >> 3;
    const int nb   = swb & 7;
    const int nblk = nb * BN;

    __shared__ __align__(16) unsigned char wlds[BN * 1024];  // 64KB bf16 W-tile
    __shared__ int srow[SROWN];
    __shared__ int chunkinfo[NCHUNK];
    __shared__ int stotal;

    const int tid  = threadIdx.x;
    const int lane = tid & 63;
    const int wid  = tid >> 6;

    // ---- issue W loads first: latency hides under prep (T14 issue-early) ----
    const float* wbase = weight + (size_t)e * (NF * KF) + (size_t)nblk * KF;
    float4 wv[16];
#pragma unroll
    for (int j = 0; j < 16; ++j)      // slot s=j*512+tid: fully coalesced 1KB/wave/instr
        wv[j] = *(const float4*)(wbase + (size_t)(j * 512 + tid) * 4);

    // ---- prep: ballot-rank tokens of expert e (r6-proven, 512-thread form) ----
    int g[8];
#pragma unroll
    for (int i = 0; i < 8; ++i) g[i] = gate[(wid * 8 + i) * 64 + lane];
    if (tid < SROWN) srow[tid] = -1;
#pragma unroll
    for (int i = 0; i < 8; ++i) {
        unsigned long long m = __ballot(g[i] == e);
        if (lane == i) chunkinfo[wid * 8 + i] = __popcll(m);
    }
    __syncthreads();
    if (tid < NCHUNK) {               // wave 0: inclusive scan of 64 chunk counts
        int c = chunkinfo[tid];
        int x = c;
#pragma unroll
        for (int d = 1; d < 64; d <<= 1) {
            int u = __shfl_up(x, d, 64);
            if (lane >= d) x += u;
        }
        chunkinfo[tid] = x - c;       // exclusive base
        if (tid == NCHUNK - 1) stotal = x;
    }
    __syncthreads();
#pragma unroll
    for (int i = 0; i < 8; ++i) {
        unsigned long long m = __ballot(g[i] == e);
        int r = chunkinfo[wid * 8 + i] + __popcll(m & ((1ull << lane) - 1ull));
        if (g[i] == e && r < SROWN) srow[r] = (wid * 8 + i) * 64 + lane;
    }

    // ---- convert W to bf16, write swizzled LDS (once) ----
#pragma unroll
    for (int j = 0; j < 16; ++j) {
        int s   = j * 512 + tid;
        int col = s >> 7;             // 128 float4 per 512-float row
        int k4  = s & 127;
        uint2 p = make_uint2(cvt2(wv[j].x, wv[j].y), cvt2(wv[j].z, wv[j].w));
        *(uint2*)(wlds + swzW(col, k4 * 8)) = p;
    }
    __syncthreads();                  // last barrier in the kernel

    const int total = stotal;

    // ---- K-loop: wave owns 16 token-rows x 64 cols; A direct-from-global ----
    for (int p = 0; p < 2; ++p) {
        if (p * 128 >= total) break;  // block-uniform
        const int rank0 = p * 128 + wid * 16;
        const int ar = srow[rank0 + (lane & 15)];
        const float* ap = inp + (size_t)(ar < 0 ? 0 : ar) * KF + 8 * (lane >> 4);

        f32x4 acc[4];
#pragma unroll
        for (int ni = 0; ni < 4; ++ni) acc[ni] = (f32x4)(0.f);

        // depth-2 rotating prefetch; all indices compile-time after full unroll
        float4 ab[3][2];
#pragma unroll
        for (int q = 0; q < 2; ++q) {
            ab[q][0] = *(const float4*)(ap + q * 32);
            ab[q][1] = *(const float4*)(ap + q * 32 + 4);
        }
#pragma unroll
        for (int kt = 0; kt < 16; ++kt) {
            if (kt + 2 < 16) {
                ab[(kt + 2) % 3][0] = *(const float4*)(ap + (kt + 2) * 32);
                ab[(kt + 2) % 3][1] = *(const float4*)(ap + (kt + 2) * 32 + 4);
            }
            bf16x8 af;
            {
                float4 lo = ab[kt % 3][0], hi = ab[kt % 3][1];
                union { unsigned u[4]; bf16x8 v; } r;
                r.u[0] = cvt2(lo.x, lo.y); r.u[1] = cvt2(lo.z, lo.w);
                r.u[2] = cvt2(hi.x, hi.y); r.u[3] = cvt2(hi.z, hi.w);
                af = r.v;
            }
            const int kbyte = kt * 64 + 16 * (lane >> 4);
#pragma unroll
            for (int ni = 0; ni < 4; ++ni) {
                bf16x8 bfr = *(const bf16x8*)(wlds + swzW(ni * 16 + (lane & 15), kbyte));
                acc[ni] = __builtin_amdgcn_mfma_f32_16x16x32_bf16(af, bfr, acc[ni], 0, 0, 0);
            }
        }

        // epilogue: D frag col=lane&15 (n), row=(lane>>4)*4+q (m)  [m89-verified]
#pragma unroll
        for (int q = 0; q < 4; ++q) {
            int rk  = rank0 + (lane >> 4) * 4 + q;
            int row = srow[rk];
            if (row >= 0) {
#pragma unroll
                for (int ni = 0; ni < 4; ++ni)
                    out[(size_t)row * NF + nblk + ni * 16 + (lane & 15)] = acc[ni][q];
            }
        }
    }
}

extern "C" void kernel_launch(void* const* d_in, const int* in_sizes, int n_in,
                              void* d_out, int out_size, void* d_ws, size_t ws_size,
                              hipStream_t stream) {
    const float* inp    = (const float*)d_in[0];
    const int*   gate   = (const int*)d_in[1];
    const float* weight = (const float*)d_in[2];
    float*       out    = (float*)d_out;

    moe_fused<<<NWG, 512, 0, stream>>>(inp, gate, weight, out);
}